// Round 16
// baseline (370.286 us; speedup 1.0000x reference)
//
#include <hip/hip_runtime.h>

typedef __attribute__((ext_vector_type(8))) int i32x8;
typedef __attribute__((ext_vector_type(16))) float f32x16;
typedef unsigned int u32;
typedef unsigned char u8;

#define NN 1024
#define ETOT 523776
#define EPSV 1e-5f

// LDS layout (bytes)
#define L_PSUM 0      /* [64][12] f32 = 3072 */
#define L_PSQ  3072   /* 3072 */
#define L_B1   6144   /* f32[512] = b1*16; reused for epi partials [64][8] after B2 */
#define L_GBW  8192   /* float4[256] = {G, BB, W3, 0} = 4096 */
#define L_TILE 12288  /* h1 fp8 [kq8][kh2][sub4][e64][8B] = 32768 */
#define L_A1   45056  /* A1 fp8 [kq4][kh2][sub4][e64][8B] = 16384 (de-aliased) */
#define L_TOTAL 61440 /* 2 blocks/CU */

#define SCL1 0x7F7F7F7F   /* e8m0 2^0 */
#define SCL2 0x80808080   /* e8m0 2^1 (diff k-chunks: staged x2, scaled x2 -> x4) */

__device__ __forceinline__ u32 pk4fp8(float a, float b, float c, float d) {
  int p = __builtin_amdgcn_cvt_pk_fp8_f32(a, b, 0, false);
  p = __builtin_amdgcn_cvt_pk_fp8_f32(c, d, p, true);
  return (u32)p;
}

struct u4x2 { uint4 a, b; };
struct u2x4 { uint2 a, b, c, d; };
__device__ __forceinline__ i32x8 ldg32(const u8* p) {
  u4x2 t; t.a = *(const uint4*)p; t.b = *(const uint4*)(p + 16);
  return __builtin_bit_cast(i32x8, t);
}
__device__ __forceinline__ i32x8 lds32(const char* base, int e8) {
  u2x4 t;
  t.a = *(const uint2*)(base + e8);
  t.b = *(const uint2*)(base + 512 + e8);
  t.c = *(const uint2*)(base + 1024 + e8);
  t.d = *(const uint2*)(base + 1536 + e8);
  return __builtin_bit_cast(i32x8, t);
}
__device__ __forceinline__ f32x16 mfma64(i32x8 A, i32x8 B, f32x16 C, int sB) {
  return __builtin_amdgcn_mfma_scale_f32_32x32x64_f8f6f4(A, B, C, 0, 0, 0, SCL1, 0, sB);
}

// ---- prep: W1f, W2f fragment-major fp8 x64; emb2 = 2*emb ----
__global__ void prep_w(const float* __restrict__ W1, const float* __restrict__ W2,
                       const float* __restrict__ gammav, const float* __restrict__ emb,
                       u8* __restrict__ W1f, u8* __restrict__ W2f, float* __restrict__ emb2) {
  int idx = blockIdx.x*256 + threadIdx.x;        // [0, 131072)
  { int c = idx >> 8, k = idx & 255;
    float v = W1[k*512 + c] * 64.f;
    int p = __builtin_amdgcn_cvt_pk_fp8_f32(v, 0.f, 0, false);
    W1f[(c>>5)*8192 + (k>>6)*2048 + ((k>>5)&1)*1024 + (c&31)*32 + (k&31)] = (u8)(p & 0xff); }
  { int o = idx >> 9, c = idx & 511;
    float v = gammav[c] * W2[c*256 + o] * 64.f;
    int p = __builtin_amdgcn_cvt_pk_fp8_f32(v, 0.f, 0, false);
    W2f[(o>>5)*16384 + (c>>6)*2048 + ((c>>5)&1)*1024 + (o&31)*32 + (c&31)] = (u8)(p & 0xff); }
  emb2[idx] = emb[idx] * 2.f;
}

// ---- prep: GBW[o] = {sum_c gamma*W2, b2 + sum_c beta*W2, W3, 0} ----
__global__ void prep_vec(const float* __restrict__ W2, const float* __restrict__ gammav,
                         const float* __restrict__ betav, const float* __restrict__ b2v,
                         const float* __restrict__ w3v, float4* __restrict__ GBWv) {
  int o = blockIdx.x, t = threadIdx.x;
  float g = 0.f, bb = 0.f;
  for (int c = t; c < 512; c += 64) {
    float w = W2[c*256 + o];
    g  += gammav[c] * w;
    bb += betav[c]  * w;
  }
  #pragma unroll
  for (int off = 1; off < 64; off <<= 1) {
    g  += __shfl_xor(g,  off, 64);
    bb += __shfl_xor(bb, off, 64);
  }
  if (t == 0) GBWv[o] = make_float4(g, bb + b2v[o], w3v[o], 0.f);
}

// ---- main: 8-wave block = 64 edges; swapped GEMMs, MX K=64 fp8, 3 barriers ----
__launch_bounds__(512, 4)
__global__ void edge_main(const float* __restrict__ emb2,
                          const float* __restrict__ b1v,
                          const float* __restrict__ b3v,
                          const float4* __restrict__ GBWv,
                          const u8* __restrict__ W1f,
                          const u8* __restrict__ W2f,
                          float* __restrict__ out) {
  extern __shared__ char smem[];
  float* psum = (float*)(smem + L_PSUM);         // [64][12]
  float* psq  = (float*)(smem + L_PSQ);
  float* sb1  = (float*)(smem + L_B1);           // b1*16; later epi partials
  float4* sgbw= (float4*)(smem + L_GBW);
  char*  tile = smem + L_TILE;                   // h1
  char*  A1   = smem + L_A1;                     // A1 (separate region)

  const int tid  = threadIdx.x;
  const int w    = tid >> 6;
  const int lane = tid & 63;
  const int l31  = lane & 31;
  const int hi   = lane >> 5;

  // exact upper-triangle tile mapping: 8256 blocks
  int kblk = blockIdx.x;
  int bi = (int)((257.0f - sqrtf(66049.0f - 8.0f*(float)kblk)) * 0.5f);
  bi = bi < 0 ? 0 : (bi > 127 ? 127 : bi);
  while (bi*128 - bi*(bi-1)/2 > kblk) --bi;
  while ((bi+1)*128 - (bi+1)*bi/2 <= kblk) ++bi;
  const int bj = bi + (kblk - (bi*128 - bi*(bi-1)/2));
  const int i0 = bi*8, j0 = bj*8;

  // ---- stage A1 fp8: wave w -> k-chunk [w*32,+32); diff staged x2, prod x4 ----
  {
    const int e  = lane;
    const int d0 = (w & 3) * 32;
    const float4* pei = (const float4*)(emb2 + (i0 + (e>>3))*128 + d0);
    const float4* pej = (const float4*)(emb2 + (j0 + (e&7))*128 + d0);
    char* base = A1 + (w>>1)*4096 + (w&1)*2048 + e*8;
    #pragma unroll
    for (int s = 0; s < 4; ++s) {
      float4 x0 = pei[s*2], x1 = pei[s*2+1];
      float4 y0 = pej[s*2], y1 = pej[s*2+1];
      uint2 pk;
      if (w < 4) {                               // diff: (2x - 2y) = 2*true
        pk.x = pk4fp8(x0.x-y0.x, x0.y-y0.y, x0.z-y0.z, x0.w-y0.w);
        pk.y = pk4fp8(x1.x-y1.x, x1.y-y1.y, x1.z-y1.z, x1.w-y1.w);
      } else {                                   // prod: 2x*2y = 4*true
        pk.x = pk4fp8(x0.x*y0.x, x0.y*y0.y, x0.z*y0.z, x0.w*y0.w);
        pk.y = pk4fp8(x1.x*y1.x, x1.y*y1.y, x1.z*y1.z, x1.w*y1.w);
      }
      *(uint2*)(base + s*512) = pk;
    }
  }
  sb1[tid] = b1v[tid] * 16.f;
  if (tid < 256) sgbw[tid] = GBWv[tid];
  __syncthreads();                               // B0

  f32x16 z16;
  #pragma unroll
  for (int i = 0; i < 16; ++i) z16[i] = 0.f;

  float sumS0 = 0.f, sqS0 = 0.f, sumS1 = 0.f, sqS1 = 0.f;
  f32x16 A0, A1acc;

  auto h1pass = [&](int cb, const f32x16& E0, const f32x16& E1) {
    char* dbase = tile + (cb>>1)*4096 + (cb&1)*2048 + hi*4;
    #pragma unroll
    for (int g = 0; g < 4; ++g) {
      const int c0 = cb*32 + g*8 + hi*4;
      const float4 b4 = *(const float4*)(sb1 + c0);
      char* dst = dbase + g*512;
      {
        float v0 = fmaxf(fmaf(E0[g*4+0], 0.0625f, b4.x), 0.f);
        float v1 = fmaxf(fmaf(E0[g*4+1], 0.0625f, b4.y), 0.f);
        float v2 = fmaxf(fmaf(E0[g*4+2], 0.0625f, b4.z), 0.f);
        float v3 = fmaxf(fmaf(E0[g*4+3], 0.0625f, b4.w), 0.f);
        *(u32*)(dst + l31*8) = pk4fp8(v0, v1, v2, v3);
        sumS0 += (v0+v1)+(v2+v3);
        sqS0 = fmaf(v0,v0,sqS0); sqS0 = fmaf(v1,v1,sqS0);
        sqS0 = fmaf(v2,v2,sqS0); sqS0 = fmaf(v3,v3,sqS0);
      }
      {
        float v0 = fmaxf(fmaf(E1[g*4+0], 0.0625f, b4.x), 0.f);
        float v1 = fmaxf(fmaf(E1[g*4+1], 0.0625f, b4.y), 0.f);
        float v2 = fmaxf(fmaf(E1[g*4+2], 0.0625f, b4.z), 0.f);
        float v3 = fmaxf(fmaf(E1[g*4+3], 0.0625f, b4.w), 0.f);
        *(u32*)(dst + (l31+32)*8) = pk4fp8(v0, v1, v2, v3);
        sumS1 += (v0+v1)+(v2+v3);
        sqS1 = fmaf(v0,v0,sqS1); sqS1 = fmaf(v1,v1,sqS1);
        sqS1 = fmaf(v2,v2,sqS1); sqS1 = fmaf(v3,v3,sqS1);
      }
    }
  };

  const u8* w1base = W1f + hi*1024 + l31*32;

  // ---- G1 pass 0: cb = w ----
  A0 = z16; A1acc = z16;
  #pragma unroll
  for (int kq = 0; kq < 4; ++kq) {
    const int sB = (kq < 2) ? SCL2 : SCL1;       // diff chunks get extra x2
    i32x8 af = ldg32(w1base + w*8192 + kq*2048);
    const char* bbp = A1 + kq*4096 + hi*2048;
    i32x8 bf0 = lds32(bbp, l31*8);
    i32x8 bf1 = lds32(bbp, (l31+32)*8);
    A0    = mfma64(af, bf0, A0, sB);
    A1acc = mfma64(af, bf1, A1acc, sB);
  }
  h1pass(w, A0, A1acc);

  // ---- G1 pass 1: cb = w + 8 ----
  A0 = z16; A1acc = z16;
  #pragma unroll
  for (int kq = 0; kq < 4; ++kq) {
    const int sB = (kq < 2) ? SCL2 : SCL1;
    i32x8 af = ldg32(w1base + (w+8)*8192 + kq*2048);
    const char* bbp = A1 + kq*4096 + hi*2048;
    i32x8 bf0 = lds32(bbp, l31*8);
    i32x8 bf1 = lds32(bbp, (l31+32)*8);
    A0    = mfma64(af, bf0, A0, sB);
    A1acc = mfma64(af, bf1, A1acc, sB);
  }
  h1pass(w + 8, A0, A1acc);                      // h1 region only: no barrier needed

  // LN partials
  sumS0 += __shfl_xor(sumS0, 32, 64);  sqS0 += __shfl_xor(sqS0, 32, 64);
  sumS1 += __shfl_xor(sumS1, 32, 64);  sqS1 += __shfl_xor(sqS1, 32, 64);
  if (hi == 0) {
    psum[l31*12 + w] = sumS0;       psq[l31*12 + w] = sqS0;
    psum[(l31+32)*12 + w] = sumS1;  psq[(l31+32)*12 + w] = sqS1;
  }
  __syncthreads();                               // B2: h1 + partials visible

  // ---- in-lane stats (stored h1 = 16x true) ----
  float sc2A, smA, sc2B, smB;
  {
    float4 s0 = *(const float4*)(psum + l31*12);
    float4 s1 = *(const float4*)(psum + l31*12 + 4);
    float4 q0 = *(const float4*)(psq  + l31*12);
    float4 q1 = *(const float4*)(psq  + l31*12 + 4);
    float su = ((s0.x+s0.y)+(s0.z+s0.w)) + ((s1.x+s1.y)+(s1.z+s1.w));
    float qu = ((q0.x+q0.y)+(q0.z+q0.w)) + ((q1.x+q1.y)+(q1.z+q1.w));
    float mu = su * (1.f/8192.f);
    float sc = rsqrtf(qu * (1.f/131072.f) - mu*mu + EPSV);
    sc2A = sc * (1.f/1024.f); smA = mu * sc;
    s0 = *(const float4*)(psum + (l31+32)*12);
    s1 = *(const float4*)(psum + (l31+32)*12 + 4);
    q0 = *(const float4*)(psq  + (l31+32)*12);
    q1 = *(const float4*)(psq  + (l31+32)*12 + 4);
    su = ((s0.x+s0.y)+(s0.z+s0.w)) + ((s1.x+s1.y)+(s1.z+s1.w));
    qu = ((q0.x+q0.y)+(q0.z+q0.w)) + ((q1.x+q1.y)+(q1.z+q1.w));
    mu = su * (1.f/8192.f);
    sc = rsqrtf(qu * (1.f/131072.f) - mu*mu + EPSV);
    sc2B = sc * (1.f/1024.f); smB = mu * sc;
  }

  // ---- G2: wave owns o-chunk w (32 o); K=512 = 8 MX instrs/acc ----
  f32x16 C0 = z16, C1 = z16;
  {
    const u8* w2base = W2f + w*16384 + hi*1024 + l31*32;
    #pragma unroll
    for (int kq = 0; kq < 8; ++kq) {
      i32x8 a = ldg32(w2base + kq*2048);
      const char* bbp = tile + kq*4096 + hi*2048;
      i32x8 b0 = lds32(bbp, l31*8);
      i32x8 b1 = lds32(bbp, (l31+32)*8);
      C0 = mfma64(a, b0, C0, SCL1);
      C1 = mfma64(a, b1, C1, SCL1);
    }
  }

  // ---- epilogue: LN-affine + relu + W3 dot via packed GBW ----
  {
    float p0 = 0.f, p1 = 0.f;
    #pragma unroll
    for (int rg = 0; rg < 16; ++rg) {
      const int o = w*32 + (rg&3) + 8*(rg>>2) + 4*hi;
      const float4 t = sgbw[o];
      float t0 = fmaxf(fmaf(sc2A, C0[rg], fmaf(-smA, t.x, t.y)), 0.f);
      p0 = fmaf(t0, t.z, p0);
      float t1 = fmaxf(fmaf(sc2B, C1[rg], fmaf(-smB, t.x, t.y)), 0.f);
      p1 = fmaf(t1, t.z, p1);
    }
    p0 += __shfl_xor(p0, 32, 64);
    p1 += __shfl_xor(p1, 32, 64);
    if (hi == 0) {                               // sb1 reuse: b1 reads all pre-B2
      sb1[l31*8 + w] = p0;
      sb1[(l31+32)*8 + w] = p1;
    }
  }
  __syncthreads();                               // B3

  // ---- flush logits + pairs ----
  if (tid < 64) {
    float4 s0 = *(const float4*)(sb1 + tid*8);
    float4 s1 = *(const float4*)(sb1 + tid*8 + 4);
    float logit = ((s0.x+s0.y)+(s0.z+s0.w)) + ((s1.x+s1.y)+(s1.z+s1.w)) + b3v[0];
    int a = tid >> 3, b = tid & 7;
    int i = i0 + a, j = j0 + b;
    if (i < j) {
      int e = i*(2*NN - i - 1)/2 + (j - i - 1);
      out[e] = logit;
      out[ETOT + 2*e]     = (float)i;
      out[ETOT + 2*e + 1] = (float)j;
    }
  }
}

extern "C" void kernel_launch(void* const* d_in, const int* in_sizes, int n_in,
                              void* d_out, int out_size, void* d_ws, size_t ws_size,
                              hipStream_t stream) {
  const float* emb   = (const float*)d_in[0];
  const float* W1    = (const float*)d_in[1];
  const float* b1    = (const float*)d_in[2];
  const float* gamma = (const float*)d_in[3];
  const float* beta  = (const float*)d_in[4];
  const float* W2    = (const float*)d_in[5];
  const float* b2    = (const float*)d_in[6];
  const float* W3    = (const float*)d_in[7];
  const float* b3    = (const float*)d_in[8];

  char* ws   = (char*)d_ws;
  u8*  W1f = (u8*)ws;                            // 128 KiB
  u8*  W2f = (u8*)(ws + 131072);                 // 128 KiB
  float4* GBWv = (float4*)(ws + 262144);         // 4 KiB
  float* emb2  = (float*)(ws + 266240);          // 512 KiB

  (void)hipFuncSetAttribute((const void*)edge_main,
                            hipFuncAttributeMaxDynamicSharedMemorySize, L_TOTAL);

  prep_w<<<512, 256, 0, stream>>>(W1, W2, gamma, emb, W1f, W2f, emb2);
  prep_vec<<<256, 64, 0, stream>>>(W2, gamma, beta, b2, W3, GBWv);
  edge_main<<<8256, 512, L_TOTAL, stream>>>(emb2, b1, b3, GBWv,
                                            W1f, W2f, (float*)d_out);
}

// Round 17
// 205.127 us; speedup vs baseline: 1.8051x; 1.8051x over previous
//
#include <hip/hip_runtime.h>

typedef __attribute__((ext_vector_type(8))) int i32x8;
typedef __attribute__((ext_vector_type(16))) float f32x16;
typedef unsigned int u32;
typedef unsigned char u8;

#define NN 1024
#define ETOT 523776
#define EPSV 1e-5f

// LDS layout (bytes)
#define L_PSUM 0      /* [64][12] f32 = 3072 (cols 0..7 used, pad) */
#define L_PSQ  3072   /* 3072 */
#define L_B1   6144   /* f32[512] = b1*16; reused for epi partials [64][8] after B2 */
#define L_G    8192   /* 1024 */
#define L_BB   9216   /* 1024 */
#define L_W3   10240  /* 1024 */
#define L_TILE 11264  /* 32 KiB: h1 fp8 [kq8][kh2][sub4][e64][8B]; A1 at +16384 (aliased under h1 kq4..7) */
#define L_TOTAL 44032

#define SCL1 0x7F7F7F7F   /* e8m0 = 2^0 in every byte */

__device__ __forceinline__ u32 pk4fp8(float a, float b, float c, float d) {
  int p = __builtin_amdgcn_cvt_pk_fp8_f32(a, b, 0, false);
  p = __builtin_amdgcn_cvt_pk_fp8_f32(c, d, p, true);
  return (u32)p;
}
__device__ __forceinline__ i32x8 ldg32(const u8* p) {
  uint4 lo = *(const uint4*)p;
  uint4 hi = *(const uint4*)(p + 16);
  i32x8 r;
  r[0]=(int)lo.x; r[1]=(int)lo.y; r[2]=(int)lo.z; r[3]=(int)lo.w;
  r[4]=(int)hi.x; r[5]=(int)hi.y; r[6]=(int)hi.z; r[7]=(int)hi.w;
  return r;
}
__device__ __forceinline__ i32x8 lds32(const char* base, int e8) {
  uint2 s0 = *(const uint2*)(base + e8);
  uint2 s1 = *(const uint2*)(base + 512 + e8);
  uint2 s2 = *(const uint2*)(base + 1024 + e8);
  uint2 s3 = *(const uint2*)(base + 1536 + e8);
  i32x8 r;
  r[0]=(int)s0.x; r[1]=(int)s0.y; r[2]=(int)s1.x; r[3]=(int)s1.y;
  r[4]=(int)s2.x; r[5]=(int)s2.y; r[6]=(int)s3.x; r[7]=(int)s3.y;
  return r;
}
#define MFMA64(A,B,C) __builtin_amdgcn_mfma_scale_f32_32x32x64_f8f6f4((A),(B),(C),0,0,0,SCL1,0,SCL1)

// ---- prep: W1 -> [cb16][kq4][kh2][c32][32B] fp8 x64 ; W2*gamma -> [ob8][kq8][kh2][o32][32B] fp8 x64 ----
__global__ void prep_w(const float* __restrict__ W1, const float* __restrict__ W2,
                       const float* __restrict__ gammav,
                       u8* __restrict__ W1f, u8* __restrict__ W2f) {
  int idx = blockIdx.x*256 + threadIdx.x;
  { int c = idx >> 8, k = idx & 255;
    float v = W1[k*512 + c] * 64.f;
    int p = __builtin_amdgcn_cvt_pk_fp8_f32(v, 0.f, 0, false);
    W1f[(c>>5)*8192 + (k>>6)*2048 + ((k>>5)&1)*1024 + (c&31)*32 + (k&31)] = (u8)(p & 0xff); }
  { int o = idx >> 9, c = idx & 511;
    float v = gammav[c] * W2[c*256 + o] * 64.f;
    int p = __builtin_amdgcn_cvt_pk_fp8_f32(v, 0.f, 0, false);
    W2f[(o>>5)*16384 + (c>>6)*2048 + ((c>>5)&1)*1024 + (o&31)*32 + (c&31)] = (u8)(p & 0xff); }
}

__global__ void prep_vec(const float* __restrict__ W2, const float* __restrict__ gammav,
                         const float* __restrict__ betav, const float* __restrict__ b2v,
                         float* __restrict__ Gv, float* __restrict__ BBv) {
  int o = blockIdx.x, t = threadIdx.x;
  float g = 0.f, bb = 0.f;
  for (int c = t; c < 512; c += 64) {
    float w = W2[c*256 + o];
    g  += gammav[c] * w;
    bb += betav[c]  * w;
  }
  #pragma unroll
  for (int off = 1; off < 64; off <<= 1) {
    g  += __shfl_xor(g,  off, 64);
    bb += __shfl_xor(bb, off, 64);
  }
  if (t == 0) { Gv[o] = g; BBv[o] = bb + b2v[o]; }
}

// ---- main: 8-wave (512-thr) block = 64 edges; swapped GEMMs, MX K=64 fp8, 2-acc waves ----
__launch_bounds__(512, 4)
__global__ void edge_main(const float* __restrict__ emb,
                          const float* __restrict__ b1v,
                          const float* __restrict__ b3v,
                          const float* __restrict__ w3v,
                          const float* __restrict__ Gv,
                          const float* __restrict__ BBv,
                          const u8* __restrict__ W1f,
                          const u8* __restrict__ W2f,
                          float* __restrict__ out) {
  extern __shared__ char smem[];
  float* psum = (float*)(smem + L_PSUM);         // [64][12]
  float* psq  = (float*)(smem + L_PSQ);
  float* sb1  = (float*)(smem + L_B1);           // b1*16; later epi partials
  float* sG   = (float*)(smem + L_G);
  float* sBB  = (float*)(smem + L_BB);
  float* sw3  = (float*)(smem + L_W3);
  char*  tile = smem + L_TILE;                   // h1 [kq8][kh2][sub4][e64][8B]
  char*  A1   = tile + 16384;                    // A1 [kq4][kh2][sub4][e64][8B]

  const int tid  = threadIdx.x;
  const int w    = tid >> 6;                     // wave 0..7
  const int lane = tid & 63;
  const int l31  = lane & 31;
  const int hi   = lane >> 5;

  // exact upper-triangle tile mapping: 8256 blocks
  int kblk = blockIdx.x;
  int bi = (int)((257.0f - sqrtf(66049.0f - 8.0f*(float)kblk)) * 0.5f);
  bi = bi < 0 ? 0 : (bi > 127 ? 127 : bi);
  while (bi*128 - bi*(bi-1)/2 > kblk) --bi;
  while ((bi+1)*128 - (bi+1)*bi/2 <= kblk) ++bi;
  const int bj = bi + (kblk - (bi*128 - bi*(bi-1)/2));
  const int i0 = bi*8, j0 = bj*8;

  // ---- stage A1 fp8 (x4): wave w -> k-chunk [w*32, w*32+32) for all 64 edges ----
  {
    const int e  = lane;
    const int d0 = (w & 3) * 32;                 // feature base
    const float4* pei = (const float4*)(emb + (i0 + (e>>3))*128 + d0);
    const float4* pej = (const float4*)(emb + (j0 + (e&7))*128 + d0);
    char* base = A1 + (w>>1)*4096 + (w&1)*2048 + e*8;
    #pragma unroll
    for (int s = 0; s < 4; ++s) {                // sub = 8 k each
      float4 x0 = pei[s*2], x1 = pei[s*2+1];
      float4 y0 = pej[s*2], y1 = pej[s*2+1];
      uint2 pk;
      if (w < 4) {
        pk.x = pk4fp8((x0.x-y0.x)*4.f, (x0.y-y0.y)*4.f, (x0.z-y0.z)*4.f, (x0.w-y0.w)*4.f);
        pk.y = pk4fp8((x1.x-y1.x)*4.f, (x1.y-y1.y)*4.f, (x1.z-y1.z)*4.f, (x1.w-y1.w)*4.f);
      } else {
        pk.x = pk4fp8((x0.x*y0.x)*4.f, (x0.y*y0.y)*4.f, (x0.z*y0.z)*4.f, (x0.w*y0.w)*4.f);
        pk.y = pk4fp8((x1.x*y1.x)*4.f, (x1.y*y1.y)*4.f, (x1.z*y1.z)*4.f, (x1.w*y1.w)*4.f);
      }
      *(uint2*)(base + s*512) = pk;
    }
  }
  sb1[tid] = b1v[tid] * 16.f;                    // pre-scaled bias
  if (tid < 256) { sG[tid] = Gv[tid]; sBB[tid] = BBv[tid]; sw3[tid] = w3v[tid]; }
  __syncthreads();                               // B0

  f32x16 z16;
  #pragma unroll
  for (int i = 0; i < 16; ++i) z16[i] = 0.f;

  float sumS0 = 0.f, sqS0 = 0.f, sumS1 = 0.f, sqS1 = 0.f;
  f32x16 A0, A1acc;

  // h1-pass for c-chunk cb: lane holds 16 c x 2 edges; store = fmax(E/16 + 16*b1, 0)
  auto h1pass = [&](int cb, const f32x16& E0, const f32x16& E1) {
    char* dbase = tile + (cb>>1)*4096 + (cb&1)*2048 + hi*4;
    #pragma unroll
    for (int g = 0; g < 4; ++g) {
      const int c0 = cb*32 + g*8 + hi*4;
      const float b0 = sb1[c0+0], b1_ = sb1[c0+1], b2_ = sb1[c0+2], b3_ = sb1[c0+3];
      char* dst = dbase + g*512;
      {
        float v0 = fmaxf(fmaf(E0[g*4+0], 0.0625f, b0), 0.f);
        float v1 = fmaxf(fmaf(E0[g*4+1], 0.0625f, b1_), 0.f);
        float v2 = fmaxf(fmaf(E0[g*4+2], 0.0625f, b2_), 0.f);
        float v3 = fmaxf(fmaf(E0[g*4+3], 0.0625f, b3_), 0.f);
        *(u32*)(dst + l31*8) = pk4fp8(v0, v1, v2, v3);
        sumS0 += (v0+v1)+(v2+v3);
        sqS0 = fmaf(v0,v0,sqS0); sqS0 = fmaf(v1,v1,sqS0);
        sqS0 = fmaf(v2,v2,sqS0); sqS0 = fmaf(v3,v3,sqS0);
      }
      {
        float v0 = fmaxf(fmaf(E1[g*4+0], 0.0625f, b0), 0.f);
        float v1 = fmaxf(fmaf(E1[g*4+1], 0.0625f, b1_), 0.f);
        float v2 = fmaxf(fmaf(E1[g*4+2], 0.0625f, b2_), 0.f);
        float v3 = fmaxf(fmaf(E1[g*4+3], 0.0625f, b3_), 0.f);
        *(u32*)(dst + (l31+32)*8) = pk4fp8(v0, v1, v2, v3);
        sumS1 += (v0+v1)+(v2+v3);
        sqS1 = fmaf(v0,v0,sqS1); sqS1 = fmaf(v1,v1,sqS1);
        sqS1 = fmaf(v2,v2,sqS1); sqS1 = fmaf(v3,v3,sqS1);
      }
    }
  };

  const u8* w1base = W1f + hi*1024 + l31*32;

  // ---- G1 pass 0: cb = w ----
  A0 = z16; A1acc = z16;
  #pragma unroll
  for (int kq = 0; kq < 4; ++kq) {
    i32x8 af = ldg32(w1base + w*8192 + kq*2048);
    const char* bbp = A1 + kq*4096 + hi*2048;
    i32x8 bf0 = lds32(bbp, l31*8);
    i32x8 bf1 = lds32(bbp, (l31+32)*8);
    A0    = MFMA64(af, bf0, A0);
    A1acc = MFMA64(af, bf1, A1acc);
  }
  h1pass(w, A0, A1acc);                          // kq_h = w>>1 < 4: below A1, safe

  // ---- G1 pass 1: cb = w + 8 ----
  A0 = z16; A1acc = z16;
  #pragma unroll
  for (int kq = 0; kq < 4; ++kq) {
    i32x8 af = ldg32(w1base + (w+8)*8192 + kq*2048);
    const char* bbp = A1 + kq*4096 + hi*2048;
    i32x8 bf0 = lds32(bbp, l31*8);
    i32x8 bf1 = lds32(bbp, (l31+32)*8);
    A0    = MFMA64(af, bf0, A0);
    A1acc = MFMA64(af, bf1, A1acc);
  }
  __syncthreads();                               // B1: all A1 reads done
  h1pass(w + 8, A0, A1acc);                      // kq_h >= 4: overwrites A1 region

  // LN partials: combine hi halves, one slot per (edge, wave)
  sumS0 += __shfl_xor(sumS0, 32, 64);  sqS0 += __shfl_xor(sqS0, 32, 64);
  sumS1 += __shfl_xor(sumS1, 32, 64);  sqS1 += __shfl_xor(sqS1, 32, 64);
  if (hi == 0) {
    psum[l31*12 + w] = sumS0;       psq[l31*12 + w] = sqS0;
    psum[(l31+32)*12 + w] = sumS1;  psq[(l31+32)*12 + w] = sqS1;
  }
  __syncthreads();                               // B2: h1 + partials visible

  // ---- in-lane stats for this lane's two edges (sums are of 16*v) ----
  float sc2A, smA, sc2B, smB;
  {
    float4 s0 = *(const float4*)(psum + l31*12);
    float4 s1 = *(const float4*)(psum + l31*12 + 4);
    float4 q0 = *(const float4*)(psq  + l31*12);
    float4 q1 = *(const float4*)(psq  + l31*12 + 4);
    float su = ((s0.x+s0.y)+(s0.z+s0.w)) + ((s1.x+s1.y)+(s1.z+s1.w));
    float qu = ((q0.x+q0.y)+(q0.z+q0.w)) + ((q1.x+q1.y)+(q1.z+q1.w));
    float mu = su * (1.f/8192.f);
    float sc = rsqrtf(qu * (1.f/131072.f) - mu*mu + EPSV);
    sc2A = sc * (1.f/1024.f); smA = mu * sc;
    s0 = *(const float4*)(psum + (l31+32)*12);
    s1 = *(const float4*)(psum + (l31+32)*12 + 4);
    q0 = *(const float4*)(psq  + (l31+32)*12);
    q1 = *(const float4*)(psq  + (l31+32)*12 + 4);
    su = ((s0.x+s0.y)+(s0.z+s0.w)) + ((s1.x+s1.y)+(s1.z+s1.w));
    qu = ((q0.x+q0.y)+(q0.z+q0.w)) + ((q1.x+q1.y)+(q1.z+q1.w));
    mu = su * (1.f/8192.f);
    sc = rsqrtf(qu * (1.f/131072.f) - mu*mu + EPSV);
    sc2B = sc * (1.f/1024.f); smB = mu * sc;
  }

  // ---- G2: wave owns o-chunk w (32 o); K=512 = 8 MX instrs per acc ----
  f32x16 C0 = z16, C1 = z16;
  {
    const u8* w2base = W2f + w*16384 + hi*1024 + l31*32;
    #pragma unroll
    for (int kq = 0; kq < 8; ++kq) {
      i32x8 a = ldg32(w2base + kq*2048);
      const char* bbp = tile + kq*4096 + hi*2048;
      i32x8 b0 = lds32(bbp, l31*8);
      i32x8 b1 = lds32(bbp, (l31+32)*8);
      C0 = MFMA64(a, b0, C0);
      C1 = MFMA64(a, b1, C1);
    }
  }

  // ---- epilogue: LN-affine + relu + W3 dot (in-lane), partials -> sb1 region ----
  {
    float p0 = 0.f, p1 = 0.f;
    #pragma unroll
    for (int rg = 0; rg < 16; ++rg) {
      const int o = w*32 + (rg&3) + 8*(rg>>2) + 4*hi;
      const float gv = sG[o], bb = sBB[o], w3 = sw3[o];
      float t0 = fmaxf(fmaf(sc2A, C0[rg], fmaf(-smA, gv, bb)), 0.f);
      p0 = fmaf(t0, w3, p0);
      float t1 = fmaxf(fmaf(sc2B, C1[rg], fmaf(-smB, gv, bb)), 0.f);
      p1 = fmaf(t1, w3, p1);
    }
    p0 += __shfl_xor(p0, 32, 64);
    p1 += __shfl_xor(p1, 32, 64);
    if (hi == 0) {                               // sb1: b1 reads all pre-B2 -> safe
      sb1[l31*8 + w] = p0;
      sb1[(l31+32)*8 + w] = p1;
    }
  }
  __syncthreads();                               // B3

  // ---- flush logits + pairs ----
  if (tid < 64) {
    float4 s0 = *(const float4*)(sb1 + tid*8);
    float4 s1 = *(const float4*)(sb1 + tid*8 + 4);
    float logit = ((s0.x+s0.y)+(s0.z+s0.w)) + ((s1.x+s1.y)+(s1.z+s1.w)) + b3v[0];
    int a = tid >> 3, b = tid & 7;
    int i = i0 + a, j = j0 + b;
    if (i < j) {
      int e = i*(2*NN - i - 1)/2 + (j - i - 1);
      out[e] = logit;
      out[ETOT + 2*e]     = (float)i;
      out[ETOT + 2*e + 1] = (float)j;
    }
  }
}

extern "C" void kernel_launch(void* const* d_in, const int* in_sizes, int n_in,
                              void* d_out, int out_size, void* d_ws, size_t ws_size,
                              hipStream_t stream) {
  const float* emb   = (const float*)d_in[0];
  const float* W1    = (const float*)d_in[1];
  const float* b1    = (const float*)d_in[2];
  const float* gamma = (const float*)d_in[3];
  const float* beta  = (const float*)d_in[4];
  const float* W2    = (const float*)d_in[5];
  const float* b2    = (const float*)d_in[6];
  const float* W3    = (const float*)d_in[7];
  const float* b3    = (const float*)d_in[8];

  char* ws   = (char*)d_ws;
  u8*  W1f = (u8*)ws;                            // 128 KiB
  u8*  W2f = (u8*)(ws + 131072);                 // 128 KiB
  float* Gv  = (float*)(ws + 262144);            // 1 KiB
  float* BBv = (float*)(ws + 263168);            // 1 KiB

  (void)hipFuncSetAttribute((const void*)edge_main,
                            hipFuncAttributeMaxDynamicSharedMemorySize, L_TOTAL);

  prep_w<<<512, 256, 0, stream>>>(W1, W2, gamma, W1f, W2f);
  prep_vec<<<256, 64, 0, stream>>>(W2, gamma, beta, b2, Gv, BBv);
  edge_main<<<8256, 512, L_TOTAL, stream>>>(emb, b1, b3, W3, Gv, BBv,
                                            W1f, W2f, (float*)d_out);
}